// Round 1
// baseline (84.109 us; speedup 1.0000x reference)
//
#include <hip/hip_runtime.h>

// TorchVQC: 8-qubit statevector, B=16384, D=256, fp32 complex.
// R8: occupancy rebuild. Old layout (16 lanes/batch, 16 amps/lane) gave only
// 4096 waves = 16 waves/CU (grid-limited, 4/SIMD) -> latency-bound at ~32%
// issue efficiency. New layout: 32 lanes/batch, 8 amps/lane:
//   stored index s = (j<<5) | lane5 : lane5 = s[4:0], register j = s[7:5].
//   8192 waves, __launch_bounds__(256,7) -> 28 waves/CU resident.
// All GF(2)-relabeled masks re-projected from the verified R7 kernel
// (full 8-bit v/u masks unchanged; only the reg/lane split boundary moved):
//   ROT0 k: v=u=bit(7-k).
//   FUSED v: C0,60,30,18,0C,06,03,C1 ; u: 7F,C0,E0,F0,F8,FC,FE,FF.
//   readout rows A: E6,F3,9F,30,67,CC,99,33 (reg = A>>5, lane = A&0x1F).
// prep_gates merged: every lane computes w-gate t=lane&15 (3 sincos),
// ROT0 coefficients broadcast via v_readlane (wave-uniform -> SGPRs).
// FUSED F-matrices built once per lane for K=lane&7 (2 sincos), broadcast
// with width-8 shuffles at use — removes the x32 replicated inline prep.
// R7 sign-folding kept: runtime lane-parity sign = one XOR on giP/brP,
// compile-time per-amp sign folded into fma neg modifiers.

using f2 = __attribute__((ext_vector_type(2))) float;  // (re, im)

__device__ __forceinline__ f2 cmul2(f2 w, f2 z) {
    f2 r;
    r.x = w.x * z.x - w.y * z.y;
    r.y = w.x * z.y + w.y * z.x;
    return r;
}
__device__ __forceinline__ f2 cmadd(f2 acc, f2 w, f2 z) {
    acc.x += w.x * z.x - w.y * z.y;
    acc.y += w.x * z.y + w.y * z.x;
    return acc;
}

__device__ __forceinline__ f2 shflx(f2 v, int m) {
    f2 r; r.x = __shfl_xor(v.x, m, 64); r.y = __shfl_xor(v.y, m, 64); return r;
}

__device__ __forceinline__ float uxor(float f, unsigned u) {
    return __uint_as_float(__float_as_uint(f) ^ u);
}

// selected encoding-column entry: hi ? (s*cp, s*sp) : (c*cp, -c*sp)
__device__ __forceinline__ f2 enc_sel(float t, float p, bool hi) {
    float s_, c_, sp_, cp_;
    __sincosf(t * 0.5f, &s_, &c_);
    __sincosf(p * 0.5f, &sp_, &cp_);
    const float m = hi ? s_ : c_;
    f2 r; r.x = m * cp_; r.y = hi ? m * sp_ : -m * sp_;
    return r;
}

// SU(2) gate under relabeling, 8 amps/lane version.
// Per amp q with partner value w:  c(q) = par(q&UREG) (compile-time) ^ laneparity
//   new_r = g00r*q.r - (sigma*giP)*q.i + (sigma*brP)*w.r - g01i*w.i
//   new_i = g00r*q.i + (sigma*giP)*q.r + (sigma*brP)*w.i + g01i*w.r
template<int VREG, int VLANE, int UREG>
__device__ __forceinline__ void gateU8(f2 (&s)[8],
                                       float g00r, float giP, float brP, float g01i)
{
    if constexpr (VLANE == 0) {
        constexpr int pivot = VREG & (-VREG);
        #pragma unroll
        for (int j = 0; j < 8; ++j) {
            if ((j & pivot) != 0) continue;
            const int j2 = j ^ VREG;
            const f2 x = s[j], y = s[j2];
            {
                const bool n = (__builtin_popcount(j & UREG) & 1) != 0;
                const float gi = n ? -giP : giP, br = n ? -brP : brP;
                s[j].x = fmaf(-g01i, y.y, fmaf(br, y.x, fmaf(-gi, x.y, g00r * x.x)));
                s[j].y = fmaf( g01i, y.x, fmaf(br, y.y, fmaf( gi, x.x, g00r * x.y)));
            }
            {
                const bool n = (__builtin_popcount(j2 & UREG) & 1) != 0;
                const float gi = n ? -giP : giP, br = n ? -brP : brP;
                s[j2].x = fmaf(-g01i, x.y, fmaf(br, x.x, fmaf(-gi, y.y, g00r * y.x)));
                s[j2].y = fmaf( g01i, x.x, fmaf(br, x.y, fmaf( gi, y.x, g00r * y.y)));
            }
        }
    } else if constexpr (VREG == 0) {
        #pragma unroll
        for (int j = 0; j < 8; ++j) {
            const f2 w = shflx(s[j], VLANE);
            const f2 x = s[j];
            const bool n = (__builtin_popcount(j & UREG) & 1) != 0;
            const float gi = n ? -giP : giP, br = n ? -brP : brP;
            s[j].x = fmaf(-g01i, w.y, fmaf(br, w.x, fmaf(-gi, x.y, g00r * x.x)));
            s[j].y = fmaf( g01i, w.x, fmaf(br, w.y, fmaf( gi, x.x, g00r * x.y)));
        }
    } else {
        constexpr int pivot = VREG & (-VREG);
        #pragma unroll
        for (int j = 0; j < 8; ++j) {
            if ((j & pivot) != 0) continue;
            const int j2 = j ^ VREG;
            const f2 p1 = shflx(s[j2], VLANE);
            const f2 p2 = shflx(s[j],  VLANE);
            const f2 x = s[j], y = s[j2];
            {
                const bool n = (__builtin_popcount(j & UREG) & 1) != 0;
                const float gi = n ? -giP : giP, br = n ? -brP : brP;
                s[j].x = fmaf(-g01i, p1.y, fmaf(br, p1.x, fmaf(-gi, x.y, g00r * x.x)));
                s[j].y = fmaf( g01i, p1.x, fmaf(br, p1.y, fmaf( gi, x.x, g00r * x.y)));
            }
            {
                const bool n = (__builtin_popcount(j2 & UREG) & 1) != 0;
                const float gi = n ? -giP : giP, br = n ? -brP : brP;
                s[j2].x = fmaf(-g01i, p2.y, fmaf(br, p2.x, fmaf(-gi, y.y, g00r * y.x)));
                s[j2].y = fmaf( g01i, p2.x, fmaf(br, p2.y, fmaf( gi, y.x, g00r * y.y)));
            }
        }
    }
}

// uniform broadcast from wave lane t (t < 16, compile-time) -> SGPR
#define RL(x, t) __int_as_float(__builtin_amdgcn_readlane(__float_as_int(x), (t)))

// layer-0 Rot: coefficients wave-uniform, read from lane K's w-gate regs
#define ROT0(K, VR, VL, UR, SL) do {                                       \
    const float g0r = RL(q00r, K), g0i = RL(q00i, K);                      \
    const float g1r = RL(q01r, K), g1i = RL(q01i, K);                      \
    gateU8<VR, VL, UR>(s, g0r, uxor(g0i, SL), uxor(g1r, SL), g1i);         \
} while (0)

// fused Renc(K)+Rot(1,K): F built once per lane (K=lane&7), width-8 bcast
#define FUSED(K, VR, VL, UR, SL) do {                                      \
    const float f0r = __shfl(F00x, K, 8), f0i = __shfl(F00y, K, 8);        \
    const float f1r = __shfl(F01x, K, 8), f1i = __shfl(F01y, K, 8);        \
    gateU8<VR, VL, UR>(s, f0r, uxor(f0i, SL), uxor(f1r, SL), f1i);         \
} while (0)

__global__ __launch_bounds__(256, 7) void vqc_kernel(
    const float* __restrict__ theta,   // [B,8]
    const float* __restrict__ phi,     // [B,8]
    const float* __restrict__ jup,     // [B,28]
    const float* __restrict__ w,       // [2,8,3] vqc weights
    float* __restrict__ out,           // [B,8]
    int Btot)
{
    const int gtid  = blockIdx.x * 256 + threadIdx.x;
    const int lane  = threadIdx.x & 63;
    const int lane5 = lane & 31;
    const int bq    = gtid >> 5;                    // one batch per 32 lanes
    const int b     = bq < Btot ? bq : Btot - 1;    // clamp for loads

    // ---- w-gate prep (all lanes; lane t holds gate t=lane&15) ----
    // Rot = RZ(om)RY(th)RZ(ph): g00=c e^{-i(ph+om)/2}, g01=-s e^{+i(ph-om)/2}
    float q00r, q00i, q01r, q01i;
    {
        const int gt = lane & 15;
        const float wph = w[gt*3+0], wth = w[gt*3+1], wom = w[gt*3+2];
        float gc_, gs_, ca_, sa_, cb_, sb_;
        __sincosf(wth * 0.5f, &gs_, &gc_);
        __sincosf(0.5f * (wph + wom), &sa_, &ca_);
        __sincosf(0.5f * (wph - wom), &sb_, &cb_);
        q00r =  gc_*ca_;  q00i = -gc_*sa_;
        q01r = -gs_*cb_;  q01i = -gs_*sb_;
    }

    float th[8], ph[8];
    {
        const float4* t4 = reinterpret_cast<const float4*>(theta + (size_t)b * 8);
        const float4* p4 = reinterpret_cast<const float4*>(phi   + (size_t)b * 8);
        const float4 a = t4[0], c = t4[1], d = p4[0], e = p4[1];
        th[0]=a.x; th[1]=a.y; th[2]=a.z; th[3]=a.w;
        th[4]=c.x; th[5]=c.y; th[6]=c.z; th[7]=c.w;
        ph[0]=d.x; ph[1]=d.y; ph[2]=d.z; ph[3]=d.w;
        ph[4]=e.x; ph[5]=e.y; ph[6]=e.z; ph[7]=e.w;
    }

    // ---- distributed FUSED-gate build: this lane owns K = lane5&7 ----
    // F = Rot(1,K) . Renc(K); only F00,F01 needed (SU(2)).
    float F00x, F00y, F01x, F01y;
    {
        const int Kq = lane5 & 7;
        const float thK = theta[(size_t)b * 8 + Kq];
        const float phK = phi  [(size_t)b * 8 + Kq];
        float c_, s_, cp_, sp_;
        __sincosf(thK * 0.25f, &s_, &c_);
        __sincosf(phK * 0.25f, &sp_, &cp_);
        const f2 R00 = { __shfl(q00r, 8 + Kq, 16), __shfl(q00i, 8 + Kq, 16) };
        const f2 R01 = { __shfl(q01r, 8 + Kq, 16), __shfl(q01i, 8 + Kq, 16) };
        const f2 E00 = { c_*cp_, -c_*sp_}, E10 = { s_*cp_,  s_*sp_};
        const f2 E01 = {-s_*cp_,  s_*sp_}, E11 = { c_*cp_,  c_*sp_};
        const f2 F00 = cmadd(cmul2(R00, E00), R01, E10);
        const f2 F01 = cmadd(cmul2(R00, E01), R01, E11);
        F00x = F00.x; F00y = F00.y; F01x = F01.x; F01y = F01.y;
    }

    // lane-parity sign words (bit31) for lane-side u-mask bits
    const unsigned t16 = (unsigned)(lane5 & 16) << 27;
    const unsigned t8  = (unsigned)(lane5 & 8)  << 28;
    const unsigned t4  = (unsigned)(lane5 & 4)  << 29;
    const unsigned t2  = (unsigned)(lane5 & 2)  << 30;
    const unsigned t1  = (unsigned)(lane5 & 1)  << 31;
    const unsigned s18 = t16 ^ t8;
    const unsigned s1C = s18 ^ t4;
    const unsigned s1E = s1C ^ t2;
    const unsigned s1F = s1E ^ t1;

    // ---- lane-side encoding product over qubits 3..7 (lane bits 4..0) ----
    f2 P = enc_sel(th[3], ph[3], (lane5 & 16) != 0);
    P = cmul2(P, enc_sel(th[4], ph[4], (lane5 & 8) != 0));
    P = cmul2(P, enc_sel(th[5], ph[5], (lane5 & 4) != 0));
    P = cmul2(P, enc_sel(th[6], ph[6], (lane5 & 2) != 0));
    P = cmul2(P, enc_sel(th[7], ph[7], (lane5 & 1) != 0));

    // ---- register-side product m012 (qubits 0,1,2 <-> j bits 2,1,0) ----
    f2 m012[8];
    {
        float s0, c0, sp0, cp0;
        __sincosf(th[0]*0.5f, &s0, &c0); __sincosf(ph[0]*0.5f, &sp0, &cp0);
        const f2 A0={c0*cp0,-c0*sp0}, A1={s0*cp0,s0*sp0};
        __sincosf(th[1]*0.5f, &s0, &c0); __sincosf(ph[1]*0.5f, &sp0, &cp0);
        const f2 B0={c0*cp0,-c0*sp0}, B1={s0*cp0,s0*sp0};
        __sincosf(th[2]*0.5f, &s0, &c0); __sincosf(ph[2]*0.5f, &sp0, &cp0);
        const f2 C0={c0*cp0,-c0*sp0}, C1={s0*cp0,s0*sp0};
        #pragma unroll
        for (int a = 0; a < 8; ++a)
            m012[a] = cmul2(cmul2((a & 4) ? A1 : A0, (a & 2) ? B1 : B0),
                            (a & 1) ? C1 : C0);
    }

    // ---- IsingZZ reduction: reg qubits {0,1,2}, lane qubits {3..7} ----
    float c01, c02, c12, Q0, Q1, Q2, LL;
    {
        const float4* J4 = reinterpret_cast<const float4*>(jup + (size_t)b * 28);
        const float z3 = (lane5 & 16) ? -1.f : 1.f;
        const float z4 = (lane5 & 8)  ? -1.f : 1.f;
        const float z5 = (lane5 & 4)  ? -1.f : 1.f;
        const float z6 = (lane5 & 2)  ? -1.f : 1.f;
        const float z7 = (lane5 & 1)  ? -1.f : 1.f;
        const float4 x0 = J4[0], x1 = J4[1], x2 = J4[2], x3 = J4[3];
        const float4 x4 = J4[4], x5 = J4[5], x6 = J4[6];
        c01 = x0.x; c02 = x0.y; c12 = x1.w;
        Q0  = x0.z*z3 + x0.w*z4 + x1.x*z5 + x1.y*z6 + x1.z*z7;
        Q1  = x2.x*z3 + x2.y*z4 + x2.z*z5 + x2.w*z6 + x3.x*z7;
        Q2  = x3.y*z3 + x3.z*z4 + x3.w*z5 + x4.x*z6 + x4.y*z7;
        LL  = x4.z*(z3*z4) + x4.w*(z3*z5) + x5.x*(z3*z6) + x5.y*(z3*z7)
            + x5.z*(z4*z5) + x5.w*(z4*z6) + x6.x*(z4*z7)
            + x6.y*(z5*z6) + x6.z*(z5*z7) + x6.w*(z6*z7);
    }

    // ---- init amplitudes: product state x Ising phase ----
    f2 s[8];
    constexpr float HPI = 1.5707963267948966f;
    #pragma unroll
    for (int j = 0; j < 8; ++j) {
        f2 u = cmul2(m012[j], P);
        float S = LL;
        S += ((__builtin_popcount(j & 6) & 1) ? -c01 : c01);
        S += ((__builtin_popcount(j & 5) & 1) ? -c02 : c02);
        S += ((__builtin_popcount(j & 3) & 1) ? -c12 : c12);
        S += ((j & 4) ? -Q0 : Q0);
        S += ((j & 2) ? -Q1 : Q1);
        S += ((j & 1) ? -Q2 : Q2);
        float se, ce;
        __sincosf(-HPI * S, &se, &ce);
        s[j] = cmul2(u, (f2){ce, se});
    }

    // ---- layer-0 Rot gates (v = u = bit(7-k), re-split at 3|5) ----
    ROT0(0, 0x4, 0x00, 0x4, 0u);
    ROT0(1, 0x2, 0x00, 0x2, 0u);
    ROT0(2, 0x1, 0x00, 0x1, 0u);
    ROT0(3, 0x0, 0x10, 0x0, t16);
    ROT0(4, 0x0, 0x08, 0x0, t8);
    ROT0(5, 0x0, 0x04, 0x0, t4);
    ROT0(6, 0x0, 0x02, 0x0, t2);
    ROT0(7, 0x0, 0x01, 0x0, t1);

    // ---- CNOT-folded fused Renc+Rot1 (v: C0,60,30,18,0C,06,03,C1) ----
    FUSED(0, 0x6, 0x00, 0x3, s1F);
    FUSED(1, 0x3, 0x00, 0x6, 0u);
    FUSED(2, 0x1, 0x10, 0x7, 0u);
    FUSED(3, 0x0, 0x18, 0x7, t16);
    FUSED(4, 0x0, 0x0C, 0x7, s18);
    FUSED(5, 0x0, 0x06, 0x7, s1C);
    FUSED(6, 0x0, 0x03, 0x7, s1E);
    FUSED(7, 0x6, 0x01, 0x7, s1F);

    // ---- readout: probs, 8-point WHT over register index, lane signs ----
    float p[8];
    #pragma unroll
    for (int j = 0; j < 8; ++j) p[j] = fmaf(s[j].y, s[j].y, s[j].x * s[j].x);
    #pragma unroll
    for (int st = 1; st < 8; st <<= 1) {
        #pragma unroll
        for (int j = 0; j < 8; ++j) {
            if ((j & st) != 0) continue;
            const float a = p[j], bb = p[j | st];
            p[j] = a + bb;  p[j | st] = a - bb;
        }
    }
    // A rows: E6,F3,9F,30,67,CC,99,33 -> (reg = A>>5, lane = A&0x1F)
    float o[8];
    o[0] = (__popc(lane5 & 0x06) & 1) ? -p[7] : p[7];
    o[1] = (__popc(lane5 & 0x13) & 1) ? -p[7] : p[7];
    o[2] = (__popc(lane5 & 0x1F) & 1) ? -p[4] : p[4];
    o[3] = (__popc(lane5 & 0x10) & 1) ? -p[1] : p[1];
    o[4] = (__popc(lane5 & 0x07) & 1) ? -p[3] : p[3];
    o[5] = (__popc(lane5 & 0x0C) & 1) ? -p[6] : p[6];
    o[6] = (__popc(lane5 & 0x19) & 1) ? -p[4] : p[4];
    o[7] = (__popc(lane5 & 0x13) & 1) ? -p[1] : p[1];

    #pragma unroll
    for (int m = 1; m <= 16; m <<= 1) {
        #pragma unroll
        for (int q = 0; q < 8; ++q) o[q] += __shfl_xor(o[q], m, 64);
    }

    if (lane5 == 0 && bq < Btot) {
        float4* op = reinterpret_cast<float4*>(out + (size_t)bq * 8);
        op[0] = make_float4(o[0], o[1], o[2], o[3]);
        op[1] = make_float4(o[4], o[5], o[6], o[7]);
    }
}

extern "C" void kernel_launch(void* const* d_in, const int* in_sizes, int n_in,
                              void* d_out, int out_size, void* d_ws, size_t ws_size,
                              hipStream_t stream) {
    const float* theta = (const float*)d_in[0];
    const float* phi   = (const float*)d_in[1];
    const float* jup   = (const float*)d_in[2];
    const float* w     = (const float*)d_in[3];
    float* out = (float*)d_out;

    const int B = in_sizes[0] / 8;               // 16384
    const int blocks = (B + 7) / 8;              // 2048: 8 batches / 256-thr block
    hipLaunchKernelGGL(vqc_kernel, dim3(blocks), dim3(256), 0, stream,
                       theta, phi, jup, w, out, B);
}

// Round 2
// 78.779 us; speedup vs baseline: 1.0677x; 1.0677x over previous
//
#include <hip/hip_runtime.h>

// TorchVQC: 8-qubit statevector, B=16384, D=256, fp32 complex.
// R9: back to the verified 16-amp/lane layout (R0 masks verbatim), with the
// shuffle machinery moved OFF the LDS pipe and prep de-replicated:
//  - __shfl_xor (ds_bpermute, ~250/thread) replaced by:
//      xor 1/2/3 -> quad_perm DPP (VALU), xor 8 -> row_ror:8 DPP (VALU),
//      xor 4/6/C -> ds_swizzle (single LDS op, no address VALU).
//    LDS-pipe ops/thread: ~250 -> ~92; DPP latency ~2cy vs bpermute ~120cy
//    on the serial gate->gate chain.
//  - FUSED gate matrices built ONCE per lane (K=lane&7, R8-verified math),
//    broadcast by group-of-8 ds_swizzle; removes ~280 replicated VALU/thread.
//  - prep_gates merged in-kernel: each lane computes w-gate (lane&15);
//    ROT0 coefficients via readlane (SGPR), layer-1 fetch via swizzle 0x117.
// Layout: 4 batch elements per wave (16 lanes each), 16 amplitudes per lane.
// Stored index s = (j<<4) | lane16. CNOTs folded via GF(2) relabeling
// (v/u tables verified R2-R4); R7 SU(2) sign-folding kept.

using f2 = __attribute__((ext_vector_type(2))) float;  // (re, im)

__device__ __forceinline__ f2 cmul2(f2 w, f2 z) {
    f2 r;
    r.x = w.x * z.x - w.y * z.y;
    r.y = w.x * z.y + w.y * z.x;
    return r;
}
__device__ __forceinline__ f2 cmadd(f2 acc, f2 w, f2 z) {
    acc.x += w.x * z.x - w.y * z.y;
    acc.y += w.x * z.y + w.y * z.x;
    return acc;
}

__device__ __forceinline__ float uxor(float f, unsigned u) {
    return __uint_as_float(__float_as_uint(f) ^ u);
}

// cross-lane value of (lane ^ M), M < 16: DPP where possible, else swizzle.
template<int M>
__device__ __forceinline__ float xlane(float v) {
    const int x = __float_as_int(v);
    int r;
    if constexpr (M == 1)       // quad_perm [1,0,3,2]
        r = __builtin_amdgcn_update_dpp(x, x, 0xB1, 0xF, 0xF, false);
    else if constexpr (M == 2)  // quad_perm [2,3,0,1]
        r = __builtin_amdgcn_update_dpp(x, x, 0x4E, 0xF, 0xF, false);
    else if constexpr (M == 3)  // quad_perm [3,2,1,0]
        r = __builtin_amdgcn_update_dpp(x, x, 0x1B, 0xF, 0xF, false);
    else if constexpr (M == 8)  // row_ror:8 == xor 8 within rows of 16
        r = __builtin_amdgcn_update_dpp(x, x, 0x128, 0xF, 0xF, false);
    else                        // ds_swizzle BitMode: xor_mask<<10 | 0x1F
        r = __builtin_amdgcn_ds_swizzle(x, (M << 10) | 0x1F);
    return __int_as_float(r);
}
template<int M>
__device__ __forceinline__ f2 xshfl2(f2 v) {
    f2 r; r.x = xlane<M>(v.x); r.y = xlane<M>(v.y); return r;
}

// broadcast lane (group8_base + K) within each group of 8 (swizzle and/or mask)
#define BC8(x, K) __int_as_float(__builtin_amdgcn_ds_swizzle( \
    __float_as_int(x), ((K) << 5) | 0x18))
// fetch lane (lane & 0x17) | 8  (layer-1 gate params held by lanes 8..15 mod 16)
#define SW117(x) __int_as_float(__builtin_amdgcn_ds_swizzle(__float_as_int(x), 0x117))

// selected encoding-column entry: hi ? (s*cp, s*sp) : (c*cp, -c*sp)
__device__ __forceinline__ f2 enc_sel(float t, float p, bool hi) {
    float s_, c_, sp_, cp_;
    __sincosf(t * 0.5f, &s_, &c_);
    __sincosf(p * 0.5f, &sp_, &cp_);
    const float m = hi ? s_ : c_;
    f2 r; r.x = m * cp_; r.y = hi ? m * sp_ : -m * sp_;
    return r;
}

// SU(2) gate under relabeling (R7 sign-folding).
template<int VREG, int VLANE, int UREG>
__device__ __forceinline__ void gateU(f2 (&s)[16],
                                      float g00r, float giP, float brP, float g01i)
{
    if constexpr (VLANE == 0) {
        constexpr int pivot = VREG & (-VREG);
        #pragma unroll
        for (int j = 0; j < 16; ++j) {
            if ((j & pivot) != 0) continue;
            const int j2 = j ^ VREG;
            const f2 x = s[j], y = s[j2];
            {
                const bool n = (__builtin_popcount(j & UREG) & 1) != 0;
                const float gi = n ? -giP : giP, br = n ? -brP : brP;
                s[j].x = fmaf(-g01i, y.y, fmaf(br, y.x, fmaf(-gi, x.y, g00r * x.x)));
                s[j].y = fmaf( g01i, y.x, fmaf(br, y.y, fmaf( gi, x.x, g00r * x.y)));
            }
            {
                const bool n = (__builtin_popcount(j2 & UREG) & 1) != 0;
                const float gi = n ? -giP : giP, br = n ? -brP : brP;
                s[j2].x = fmaf(-g01i, x.y, fmaf(br, x.x, fmaf(-gi, y.y, g00r * y.x)));
                s[j2].y = fmaf( g01i, x.x, fmaf(br, x.y, fmaf( gi, y.x, g00r * y.y)));
            }
        }
    } else if constexpr (VREG == 0) {
        #pragma unroll
        for (int j = 0; j < 16; ++j) {
            const f2 w = xshfl2<VLANE>(s[j]);
            const f2 x = s[j];
            const bool n = (__builtin_popcount(j & UREG) & 1) != 0;
            const float gi = n ? -giP : giP, br = n ? -brP : brP;
            s[j].x = fmaf(-g01i, w.y, fmaf(br, w.x, fmaf(-gi, x.y, g00r * x.x)));
            s[j].y = fmaf( g01i, w.x, fmaf(br, w.y, fmaf( gi, x.x, g00r * x.y)));
        }
    } else {
        constexpr int pivot = VREG & (-VREG);
        #pragma unroll
        for (int j = 0; j < 16; ++j) {
            if ((j & pivot) != 0) continue;
            const int j2 = j ^ VREG;
            const f2 p1 = xshfl2<VLANE>(s[j2]);
            const f2 p2 = xshfl2<VLANE>(s[j]);
            const f2 x = s[j], y = s[j2];
            {
                const bool n = (__builtin_popcount(j & UREG) & 1) != 0;
                const float gi = n ? -giP : giP, br = n ? -brP : brP;
                s[j].x = fmaf(-g01i, p1.y, fmaf(br, p1.x, fmaf(-gi, x.y, g00r * x.x)));
                s[j].y = fmaf( g01i, p1.x, fmaf(br, p1.y, fmaf( gi, x.x, g00r * x.y)));
            }
            {
                const bool n = (__builtin_popcount(j2 & UREG) & 1) != 0;
                const float gi = n ? -giP : giP, br = n ? -brP : brP;
                s[j2].x = fmaf(-g01i, p2.y, fmaf(br, p2.x, fmaf(-gi, y.y, g00r * y.x)));
                s[j2].y = fmaf( g01i, p2.x, fmaf(br, p2.y, fmaf( gi, y.x, g00r * y.y)));
            }
        }
    }
}

// uniform broadcast from wave lane t (compile-time) -> SGPR
#define RL(x, t) __int_as_float(__builtin_amdgcn_readlane(__float_as_int(x), (t)))

// layer-0 Rot: coefficients wave-uniform, read from lane K's w-gate regs
#define ROT0(K, VR, VL, UR, SL) do {                                       \
    const float g0r = RL(q00r, K), g0i = RL(q00i, K);                      \
    const float g1r = RL(q01r, K), g1i = RL(q01i, K);                      \
    gateU<VR, VL, UR>(s, g0r, uxor(g0i, SL), uxor(g1r, SL), g1i);          \
} while (0)

// fused Renc(K)+Rot(1,K): F built once per lane (K=lane&7), group-8 bcast
#define FUSED(K, VR, VL, UR, SL) do {                                      \
    const float f0r = BC8(F00x, K), f0i = BC8(F00y, K);                    \
    const float f1r = BC8(F01x, K), f1i = BC8(F01y, K);                    \
    gateU<VR, VL, UR>(s, f0r, uxor(f0i, SL), uxor(f1r, SL), f1i);          \
} while (0)

__global__ __launch_bounds__(256, 4) void vqc_kernel(
    const float* __restrict__ theta,   // [B,8]
    const float* __restrict__ phi,     // [B,8]
    const float* __restrict__ jup,     // [B,28]
    const float* __restrict__ w,       // [2,8,3] vqc weights
    float* __restrict__ out,           // [B,8]
    int Btot)
{
    const int gtid   = blockIdx.x * 256 + threadIdx.x;
    const int lane   = threadIdx.x & 63;
    const int lane16 = lane & 15;
    const int bq     = gtid >> 4;                   // one batch per 16 lanes
    const int b      = bq < Btot ? bq : Btot - 1;   // clamp for loads

    // ---- w-gate prep (lane t holds gate t=lane&15; layer0=0..7, layer1=8..15)
    // Rot = RZ(om)RY(th)RZ(ph): g00=c e^{-i(ph+om)/2}, g01=-s e^{+i(ph-om)/2}
    float q00r, q00i, q01r, q01i;
    {
        const int gt = lane & 15;
        const float wph = w[gt*3+0], wth = w[gt*3+1], wom = w[gt*3+2];
        float gc_, gs_, ca_, sa_, cb_, sb_;
        __sincosf(wth * 0.5f, &gs_, &gc_);
        __sincosf(0.5f * (wph + wom), &sa_, &ca_);
        __sincosf(0.5f * (wph - wom), &sb_, &cb_);
        q00r =  gc_*ca_;  q00i = -gc_*sa_;
        q01r = -gs_*cb_;  q01i = -gs_*sb_;
    }

    // per-lane K for the fused-gate build, issue its loads early
    const int Kq = lane & 7;
    const float thK = theta[(size_t)b * 8 + Kq];
    const float phK = phi  [(size_t)b * 8 + Kq];

    float th[8], ph[8];
    {
        const float4* t4 = reinterpret_cast<const float4*>(theta + (size_t)b * 8);
        const float4* p4 = reinterpret_cast<const float4*>(phi   + (size_t)b * 8);
        const float4 a = t4[0], c = t4[1], d = p4[0], e = p4[1];
        th[0]=a.x; th[1]=a.y; th[2]=a.z; th[3]=a.w;
        th[4]=c.x; th[5]=c.y; th[6]=c.z; th[7]=c.w;
        ph[0]=d.x; ph[1]=d.y; ph[2]=d.z; ph[3]=d.w;
        ph[4]=e.x; ph[5]=e.y; ph[6]=e.z; ph[7]=e.w;
    }

    // ---- distributed FUSED-gate build (R8-verified math) ----
    // F = Rot(1,K) . Renc(K); only F00,F01 needed (SU(2)).
    float F00x, F00y, F01x, F01y;
    {
        float c_, s_, cp_, sp_;
        __sincosf(thK * 0.25f, &s_, &c_);
        __sincosf(phK * 0.25f, &sp_, &cp_);
        const f2 R00 = { SW117(q00r), SW117(q00i) };   // layer-1 gate Kq
        const f2 R01 = { SW117(q01r), SW117(q01i) };
        const f2 E00 = { c_*cp_, -c_*sp_}, E10 = { s_*cp_,  s_*sp_};
        const f2 E01 = {-s_*cp_,  s_*sp_}, E11 = { c_*cp_,  c_*sp_};
        const f2 F00 = cmadd(cmul2(R00, E00), R01, E10);
        const f2 F01 = cmadd(cmul2(R00, E01), R01, E11);
        F00x = F00.x; F00y = F00.y; F01x = F01.x; F01y = F01.y;
    }

    // lane-parity sign words (bit31) for ULANE masks used by the gate table
    const unsigned s8 = (unsigned)(lane16 & 8) << 28;
    const unsigned s4 = (unsigned)(lane16 & 4) << 29;
    const unsigned s2 = (unsigned)(lane16 & 2) << 30;
    const unsigned s1 = (unsigned)(lane16 & 1) << 31;
    const unsigned sC = s8 ^ s4;
    const unsigned sE = sC ^ s2;
    const unsigned sF = sE ^ s1;

    // ---- lane-side encoding product over qubits 4..7 ----
    f2 P = enc_sel(th[4], ph[4], (lane16 & 8) != 0);
    P = cmul2(P, enc_sel(th[5], ph[5], (lane16 & 4) != 0));
    P = cmul2(P, enc_sel(th[6], ph[6], (lane16 & 2) != 0));
    P = cmul2(P, enc_sel(th[7], ph[7], (lane16 & 1) != 0));

    // ---- register-side partial products m01 (qubits 0,1), m23 (qubits 2,3) ----
    f2 m01[4], m23[4];
    {
        float s0, c0, sp0, cp0, s1_, c1_, sp1, cp1;
        __sincosf(th[0]*0.5f, &s0, &c0); __sincosf(ph[0]*0.5f, &sp0, &cp0);
        __sincosf(th[1]*0.5f, &s1_, &c1_); __sincosf(ph[1]*0.5f, &sp1, &cp1);
        const f2 A0={c0*cp0,-c0*sp0}, A1={s0*cp0,s0*sp0};
        const f2 B0={c1_*cp1,-c1_*sp1}, B1={s1_*cp1,s1_*sp1};
        #pragma unroll
        for (int a = 0; a < 4; ++a)
            m01[a] = cmul2((a & 2) ? A1 : A0, (a & 1) ? B1 : B0);
        __sincosf(th[2]*0.5f, &s0, &c0); __sincosf(ph[2]*0.5f, &sp0, &cp0);
        __sincosf(th[3]*0.5f, &s1_, &c1_); __sincosf(ph[3]*0.5f, &sp1, &cp1);
        const f2 C0={c0*cp0,-c0*sp0}, C1={s0*cp0,s0*sp0};
        const f2 D0={c1_*cp1,-c1_*sp1}, D1={s1_*cp1,s1_*sp1};
        #pragma unroll
        for (int a = 0; a < 4; ++a)
            m23[a] = cmul2((a & 2) ? C1 : C0, (a & 1) ? D1 : D0);
    }

    // ---- IsingZZ reduction: J[28] -> c01..c23, Q0..Q3, LL ----
    float c01, c02, c03, c12, c13, c23, Q0, Q1, Q2, Q3, LL;
    {
        const float4* J4 = reinterpret_cast<const float4*>(jup + (size_t)b * 28);
        const float z4 = (lane16 & 8) ? -1.f : 1.f;
        const float z5 = (lane16 & 4) ? -1.f : 1.f;
        const float z6 = (lane16 & 2) ? -1.f : 1.f;
        const float z7 = (lane16 & 1) ? -1.f : 1.f;
        const float4 x0 = J4[0], x1 = J4[1], x2 = J4[2], x3 = J4[3];
        const float4 x4 = J4[4], x5 = J4[5], x6 = J4[6];
        c01 = x0.x; c02 = x0.y; c03 = x0.z;
        Q0  = x0.w*z4 + x1.x*z5 + x1.y*z6 + x1.z*z7;
        c12 = x1.w; c13 = x2.x;
        Q1  = x2.y*z4 + x2.z*z5 + x2.w*z6 + x3.x*z7;
        c23 = x3.y;
        Q2  = x3.z*z4 + x3.w*z5 + x4.x*z6 + x4.y*z7;
        Q3  = x4.z*z4 + x4.w*z5 + x5.x*z6 + x5.y*z7;
        LL  = x5.z*(z4*z5) + x5.w*(z4*z6) + x6.x*(z4*z7)
            + x6.y*(z5*z6) + x6.z*(z5*z7) + x6.w*(z6*z7);
    }

    // ---- init amplitudes: product state x Ising phase ----
    f2 s[16];
    constexpr float HPI = 1.5707963267948966f;
    #pragma unroll
    for (int j = 0; j < 16; ++j) {
        f2 u = cmul2(cmul2(m01[j >> 2], m23[j & 3]), P);
        float S = LL;
        S += ((__builtin_popcount(j & 0xC) & 1) ? -c01 : c01);
        S += ((__builtin_popcount(j & 0xA) & 1) ? -c02 : c02);
        S += ((__builtin_popcount(j & 0x9) & 1) ? -c03 : c03);
        S += ((__builtin_popcount(j & 0x6) & 1) ? -c12 : c12);
        S += ((__builtin_popcount(j & 0x5) & 1) ? -c13 : c13);
        S += ((__builtin_popcount(j & 0x3) & 1) ? -c23 : c23);
        S += ((j & 8) ? -Q0 : Q0);
        S += ((j & 4) ? -Q1 : Q1);
        S += ((j & 2) ? -Q2 : Q2);
        S += ((j & 1) ? -Q3 : Q3);
        float se, ce;
        __sincosf(-HPI * S, &se, &ce);
        s[j] = cmul2(u, (f2){ce, se});
    }

    // ---- layer-0 Rot gates (A = I): v = u = e_p, p = 7-k ----
    ROT0(0, 0x8, 0x0, 0x8, 0u);
    ROT0(1, 0x4, 0x0, 0x4, 0u);
    ROT0(2, 0x2, 0x0, 0x2, 0u);
    ROT0(3, 0x1, 0x0, 0x1, 0u);
    ROT0(4, 0x0, 0x8, 0x0, s8);
    ROT0(5, 0x0, 0x4, 0x0, s4);
    ROT0(6, 0x0, 0x2, 0x0, s2);
    ROT0(7, 0x0, 0x1, 0x0, s1);

    // ---- layer-0 CNOT ring folded into relabeling; RENC(k)+ROT(1,k) fused ----
    FUSED(0, 0xC, 0x0, 0x7, sF);
    FUSED(1, 0x6, 0x0, 0xC, 0u);
    FUSED(2, 0x3, 0x0, 0xE, 0u);
    FUSED(3, 0x1, 0x8, 0xF, 0u);
    FUSED(4, 0x0, 0xC, 0xF, s8);
    FUSED(5, 0x0, 0x6, 0xF, sC);
    FUSED(6, 0x0, 0x3, 0xF, sE);
    FUSED(7, 0xC, 0x1, 0xF, sF);

    // layer-1 CNOT ring folded into readout signs (final A rows, verified R2)
    // ---- readout: probs, 16-point WHT over register index, lane signs ----
    float p[16];
    #pragma unroll
    for (int j = 0; j < 16; ++j) p[j] = fmaf(s[j].y, s[j].y, s[j].x * s[j].x);
    #pragma unroll
    for (int st = 1; st < 16; st <<= 1) {
        #pragma unroll
        for (int j = 0; j < 16; ++j) {
            if ((j & st) != 0) continue;
            const float a = p[j], bb = p[j | st];
            p[j] = a + bb;  p[j | st] = a - bb;
        }
    }
    float o[8];
    o[0] = (__popc(lane16 & 0x6) & 1) ? -p[0xE] : p[0xE];
    o[1] = (__popc(lane16 & 0x3) & 1) ? -p[0xF] : p[0xF];
    o[2] = (__popc(lane16 & 0xF) & 1) ? -p[0x9] : p[0x9];
    o[3] = p[0x3];
    o[4] = (__popc(lane16 & 0x7) & 1) ? -p[0x6] : p[0x6];
    o[5] = (__popc(lane16 & 0xC) & 1) ? -p[0xC] : p[0xC];
    o[6] = (__popc(lane16 & 0x9) & 1) ? -p[0x9] : p[0x9];
    o[7] = (__popc(lane16 & 0x3) & 1) ? -p[0x3] : p[0x3];

    // cross-lane sum within the 16-lane group: DPP for 1,2,8; swizzle for 4
    #pragma unroll
    for (int q = 0; q < 8; ++q) o[q] += xlane<1>(o[q]);
    #pragma unroll
    for (int q = 0; q < 8; ++q) o[q] += xlane<2>(o[q]);
    #pragma unroll
    for (int q = 0; q < 8; ++q) o[q] += xlane<4>(o[q]);
    #pragma unroll
    for (int q = 0; q < 8; ++q) o[q] += xlane<8>(o[q]);

    if (lane16 == 0 && bq < Btot) {
        float4* op = reinterpret_cast<float4*>(out + (size_t)bq * 8);
        op[0] = make_float4(o[0], o[1], o[2], o[3]);
        op[1] = make_float4(o[4], o[5], o[6], o[7]);
    }
}

extern "C" void kernel_launch(void* const* d_in, const int* in_sizes, int n_in,
                              void* d_out, int out_size, void* d_ws, size_t ws_size,
                              hipStream_t stream) {
    const float* theta = (const float*)d_in[0];
    const float* phi   = (const float*)d_in[1];
    const float* jup   = (const float*)d_in[2];
    const float* w     = (const float*)d_in[3];
    float* out = (float*)d_out;

    const int B = in_sizes[0] / 8;               // 16384
    const int blocks = (B * 16 + 255) / 256;     // 1024: 16 batches / block
    hipLaunchKernelGGL(vqc_kernel, dim3(blocks), dim3(256), 0, stream,
                       theta, phi, jup, w, out, B);
}